// Round 2
// baseline (49.898 us; speedup 1.0000x reference)
//
#include <hip/hip_runtime.h>
#include <hip/hip_bf16.h>

// Problem constants (match reference)
constexpr int P = 8192;
constexpr int G = 4096;
constexpr int BLK = 256;
constexpr int GSPLIT = 32;          // G-dimension parallel chunks
constexpr int CHUNK = G / GSPLIT;   // 128 gaussians per chunk
constexpr int PPT = 2;              // points per thread (amortize LDS reads)
constexpr int PBLK = BLK * PPT;     // 512 points per block
constexpr float LOG2E = 1.4426950408889634f;

// ---------------------------------------------------------------------------
// Kernel 1: per-Gaussian precompute. Packs, per gaussian (5 x float4):
//   v0: mean.x, mean.y, mean.z, w00
//   v1: w11, w22, w01, w02
//   v2: w12, a0, a1, a2
//   v3: a3, a4, a5, a6
//   v4: a7, a8, 0, 0
// where wij are the Mahalanobis quadratic-form coefficients with
// (-0.5*log2(e)) and the off-diagonal 2x pre-folded, so
//   gauss = exp2( w00*dx^2 + w11*dy^2 + w22*dz^2 + w01*dx*dy + w02*dx*dz + w12*dy*dz )
// and a_k = (signed SH constant) * sh_k * sigmoid(opacity).
// ---------------------------------------------------------------------------
__global__ __launch_bounds__(256) void precomp_kernel(
    const float* __restrict__ mean, const float* __restrict__ fdc,
    const float* __restrict__ frest, const float* __restrict__ scal,
    const float* __restrict__ rot, const float* __restrict__ opac,
    float4* __restrict__ pre) {
  int g = blockIdx.x * blockDim.x + threadIdx.x;
  if (g >= G) return;

  // quaternion -> rotation (normalize like reference: q / ||q||)
  float qr = rot[g * 4 + 0], qx = rot[g * 4 + 1];
  float qy = rot[g * 4 + 2], qz = rot[g * 4 + 3];
  float qn = 1.0f / sqrtf(qr * qr + qx * qx + qy * qy + qz * qz);
  qr *= qn; qx *= qn; qy *= qn; qz *= qn;

  float R00 = 1.f - 2.f * (qy * qy + qz * qz);
  float R01 = 2.f * (qx * qy - qr * qz);
  float R02 = 2.f * (qx * qz + qr * qy);
  float R10 = 2.f * (qx * qy + qr * qz);
  float R11 = 1.f - 2.f * (qx * qx + qz * qz);
  float R12 = 2.f * (qy * qz - qr * qx);
  float R20 = 2.f * (qx * qz - qr * qy);
  float R21 = 2.f * (qy * qz + qr * qx);
  float R22 = 1.f - 2.f * (qx * qx + qy * qy);

  // inv_var = 1/(exp(s)^2), mirroring reference arithmetic
  float sc0 = expf(scal[g * 3 + 0]);
  float sc1 = expf(scal[g * 3 + 1]);
  float sc2 = expf(scal[g * 3 + 2]);
  float iv0 = 1.0f / (sc0 * sc0);
  float iv1 = 1.0f / (sc1 * sc1);
  float iv2 = 1.0f / (sc2 * sc2);

  // Sinv = R diag(iv) R^T (symmetric; 6 unique entries)
  float s00 = R00 * R00 * iv0 + R01 * R01 * iv1 + R02 * R02 * iv2;
  float s11 = R10 * R10 * iv0 + R11 * R11 * iv1 + R12 * R12 * iv2;
  float s22 = R20 * R20 * iv0 + R21 * R21 * iv1 + R22 * R22 * iv2;
  float s01 = R00 * R10 * iv0 + R01 * R11 * iv1 + R02 * R12 * iv2;
  float s02 = R00 * R20 * iv0 + R01 * R21 * iv1 + R02 * R22 * iv2;
  float s12 = R10 * R20 * iv0 + R11 * R21 * iv1 + R12 * R22 * iv2;

  // fold -0.5*log2(e) (and the 2x for off-diagonals) into the coefficients
  const float kD = -0.5f * LOG2E;   // diagonal factor
  const float kO = -LOG2E;          // off-diagonal factor (2 * -0.5)

  float alpha = 1.0f / (1.0f + expf(-opac[g]));

  // SH coefficients with constants, signs, and alpha folded in
  const float C0 = 0.28209479177387814f;
  const float C1 = 0.4886025119029199f;
  float a0 = C0 * fdc[g] * alpha;
  float a1 = -C1 * frest[g * 8 + 0] * alpha;
  float a2 =  C1 * frest[g * 8 + 1] * alpha;
  float a3 = -C1 * frest[g * 8 + 2] * alpha;
  float a4 =  1.0925484305920792f  * frest[g * 8 + 3] * alpha;
  float a5 = -1.0925484305920792f  * frest[g * 8 + 4] * alpha;
  float a6 =  0.31539156525252005f * frest[g * 8 + 5] * alpha;
  float a7 = -1.0925484305920792f  * frest[g * 8 + 6] * alpha;
  float a8 =  0.5462742152960396f  * frest[g * 8 + 7] * alpha;

  float mx = mean[g * 3 + 0], my = mean[g * 3 + 1], mz = mean[g * 3 + 2];

  pre[g * 5 + 0] = make_float4(mx, my, mz, kD * s00);
  pre[g * 5 + 1] = make_float4(kD * s11, kD * s22, kO * s01, kO * s02);
  pre[g * 5 + 2] = make_float4(kO * s12, a0, a1, a2);
  pre[g * 5 + 3] = make_float4(a3, a4, a5, a6);
  pre[g * 5 + 4] = make_float4(a7, a8, 0.f, 0.f);
}

// ---------------------------------------------------------------------------
// Kernel 2: main pair loop. Grid = (P/PBLK, GSPLIT) = (16, 32) = 512 blocks.
// Each block stages its CHUNK gaussians into LDS (10 KB); each thread owns
// PPT=2 points and loops the chunk. LDS reads are wave-uniform -> broadcast.
// ---------------------------------------------------------------------------
__global__ __launch_bounds__(BLK) void main_kernel(
    const float* __restrict__ pos, const float4* __restrict__ pre,
    float* __restrict__ partial) {
  __shared__ float4 sg[CHUNK * 5];

  const int t = threadIdx.x;
  const int p0 = blockIdx.x * PBLK + t;        // first point
  const int p1 = p0 + BLK;                     // second point
  const int c = blockIdx.y;

  const float4* src = pre + (size_t)c * CHUNK * 5;
  for (int i = t; i < CHUNK * 5; i += BLK) sg[i] = src[i];
  __syncthreads();

  const float q0x = pos[p0 * 3 + 0] * 2.0f - 1.0f;
  const float q0y = pos[p0 * 3 + 1] * 2.0f - 1.0f;
  const float q0z = pos[p0 * 3 + 2] * 2.0f - 1.0f;
  const float q1x = pos[p1 * 3 + 0] * 2.0f - 1.0f;
  const float q1y = pos[p1 * 3 + 1] * 2.0f - 1.0f;
  const float q1z = pos[p1 * 3 + 2] * 2.0f - 1.0f;

  float acc0 = 0.0f, acc1 = 0.0f;
#pragma unroll 4
  for (int gi = 0; gi < CHUNK; ++gi) {
    const float4 v0 = sg[gi * 5 + 0];
    const float4 v1 = sg[gi * 5 + 1];
    const float4 v2 = sg[gi * 5 + 2];
    const float4 v3 = sg[gi * 5 + 3];
    const float4 v4 = sg[gi * 5 + 4];

    // ---- point 0 ----
    {
      const float dx = q0x - v0.x, dy = q0y - v0.y, dz = q0z - v0.z;
      const float dxx = dx * dx, dyy = dy * dy, dzz = dz * dz;
      const float d2 = dxx + dyy + dzz;

      float m = v0.w * dxx;
      m = fmaf(v1.x, dyy, m);
      m = fmaf(v1.y, dzz, m);
      m = fmaf(v1.z, dx * dy, m);
      m = fmaf(v1.w, dx * dz, m);
      m = fmaf(v2.x, dy * dz, m);
      const float gauss = exp2f(m);

      const float inv = __builtin_amdgcn_rcpf(__builtin_amdgcn_sqrtf(d2) + 1e-8f);
      const float x = dx * inv, y = dy * inv, z = dz * inv;
      const float xx = x * x, yy = y * y, zz = z * z;
      const float xxyy = xx + yy;

      float feat = v2.y;
      feat = fmaf(v2.z, y, feat);
      feat = fmaf(v2.w, z, feat);
      feat = fmaf(v3.x, x, feat);
      feat = fmaf(v3.y, x * y, feat);
      feat = fmaf(v3.z, y * z, feat);
      feat = fmaf(v3.w, fmaf(2.f, zz, -xxyy), feat);
      feat = fmaf(v4.x, x * z, feat);
      feat = fmaf(v4.y, xx - yy, feat);

      acc0 = fmaf(gauss, feat, acc0);
    }
    // ---- point 1 ----
    {
      const float dx = q1x - v0.x, dy = q1y - v0.y, dz = q1z - v0.z;
      const float dxx = dx * dx, dyy = dy * dy, dzz = dz * dz;
      const float d2 = dxx + dyy + dzz;

      float m = v0.w * dxx;
      m = fmaf(v1.x, dyy, m);
      m = fmaf(v1.y, dzz, m);
      m = fmaf(v1.z, dx * dy, m);
      m = fmaf(v1.w, dx * dz, m);
      m = fmaf(v2.x, dy * dz, m);
      const float gauss = exp2f(m);

      const float inv = __builtin_amdgcn_rcpf(__builtin_amdgcn_sqrtf(d2) + 1e-8f);
      const float x = dx * inv, y = dy * inv, z = dz * inv;
      const float xx = x * x, yy = y * y, zz = z * z;
      const float xxyy = xx + yy;

      float feat = v2.y;
      feat = fmaf(v2.z, y, feat);
      feat = fmaf(v2.w, z, feat);
      feat = fmaf(v3.x, x, feat);
      feat = fmaf(v3.y, x * y, feat);
      feat = fmaf(v3.z, y * z, feat);
      feat = fmaf(v3.w, fmaf(2.f, zz, -xxyy), feat);
      feat = fmaf(v4.x, x * z, feat);
      feat = fmaf(v4.y, xx - yy, feat);

      acc1 = fmaf(gauss, feat, acc1);
    }
  }

  partial[(size_t)c * P + p0] = acc0;
  partial[(size_t)c * P + p1] = acc1;
}

// ---------------------------------------------------------------------------
// Kernel 3: deterministic reduction over GSPLIT partials.
// ---------------------------------------------------------------------------
__global__ __launch_bounds__(BLK) void reduce_kernel(
    const float* __restrict__ partial, float* __restrict__ out) {
  const int p = blockIdx.x * BLK + threadIdx.x;
  float s = 0.0f;
#pragma unroll
  for (int c = 0; c < GSPLIT; ++c) s += partial[(size_t)c * P + p];
  out[p] = s;
}

extern "C" void kernel_launch(void* const* d_in, const int* in_sizes, int n_in,
                              void* d_out, int out_size, void* d_ws, size_t ws_size,
                              hipStream_t stream) {
  const float* pos   = (const float*)d_in[0];  // position_rx (P,3)
  const float* mean  = (const float*)d_in[1];  // mean (G,3)
  const float* fdc   = (const float*)d_in[2];  // features_dc (G,1,1)
  const float* frest = (const float*)d_in[3];  // features_rest (G,1,8)
  const float* scal  = (const float*)d_in[4];  // scaling (G,3)
  const float* rot   = (const float*)d_in[5];  // rotation (G,4)
  const float* opac  = (const float*)d_in[6];  // opacity (G,1)
  float* out = (float*)d_out;                  // (P,1) fp32

  float4* pre = (float4*)d_ws;                            // G*5*16 = 320 KB
  float* partial = (float*)((char*)d_ws + (size_t)G * 5 * sizeof(float4));  // GSPLIT*P*4 = 1 MB

  precomp_kernel<<<G / BLK, BLK, 0, stream>>>(mean, fdc, frest, scal, rot, opac, pre);
  main_kernel<<<dim3(P / PBLK, GSPLIT), BLK, 0, stream>>>(pos, pre, partial);
  reduce_kernel<<<P / BLK, BLK, 0, stream>>>(partial, out);
}